// Round 2
// baseline (476.021 us; speedup 1.0000x reference)
//
#include <hip/hip_runtime.h>
#include <stdint.h>

// MEASUREMENT PROBE: identical kernel launched 3x back-to-back (idempotent:
// reads x only, writes identical out each time). dur_us = fixed_harness + 3*K
// => K = (dur3 - 361)/2. Kernel body is byte-identical to R1.
#define B_      16
#define C_      256
#define L_      16384
#define OL_     4096
#define OT      32
#define TL      128
#define NTHR    512
#define TPB     4
#define NBLK    ((B_ * (OL_ / OT)) / TPB)   // 512

typedef float f4 __attribute__((ext_vector_type(4)));

#define BARRIER_LGKM() do {                                   \
    asm volatile("s_waitcnt lgkmcnt(0)" ::: "memory");        \
    __builtin_amdgcn_s_barrier();                             \
    asm volatile("" ::: "memory");                            \
} while (0)

__global__ __launch_bounds__(NTHR, 4)
void havgpool_hyp_kernel(const float* __restrict__ x, float* __restrict__ out) {
    __shared__ float sP[8][TL];
    __shared__ float sA1[TL];
    __shared__ float sQ[8][OT];
    __shared__ float sInvm[OT];

    const int t     = threadIdx.x;
    const int blk   = blockIdx.x;
    const int tile0 = blk * TPB;
    const int b     = tile0 >> 7;
    const int ot0   = tile0 & 127;
    const int j     = t & 31;
    const int rbase = t >> 5;
    const int lane  = t & 63;
    const int w     = t >> 6;

    const float* src = x   + ((size_t)b * C_ * L_  + (size_t)ot0 * TL + 4 * j);
    float*       op  = out + ((size_t)b * C_ * OL_ + (size_t)ot0 * OT + j);

    f4 v[16];
    #pragma unroll
    for (int it = 0; it < 16; ++it)
        v[it] = __builtin_nontemporal_load((const f4*)(src + (size_t)(it * 16 + rbase) * L_));

    #pragma unroll
    for (int i = 0; i < TPB; ++i) {
        const float* nsrc = src + (size_t)(i + 1) * TL;

        float a0 = 0.f, a1 = 0.f, a2 = 0.f, a3 = 0.f;
        #pragma unroll
        for (int it = 0; it < 16; ++it) {
            a0 += v[it].x * v[it].x;
            a1 += v[it].y * v[it].y;
            a2 += v[it].z * v[it].z;
            a3 += v[it].w * v[it].w;
        }
        a0 += __shfl_xor(a0, 32, 64);
        a1 += __shfl_xor(a1, 32, 64);
        a2 += __shfl_xor(a2, 32, 64);
        a3 += __shfl_xor(a3, 32, 64);
        if (lane < 32) {
            sP[w][4 * j + 0] = a0;
            sP[w][4 * j + 1] = a1;
            sP[w][4 * j + 2] = a2;
            sP[w][4 * j + 3] = a3;
        }
        BARRIER_LGKM();                                   // B1

        if (t < TL) {
            float x2 = 0.f;
            #pragma unroll
            for (int k = 0; k < 8; ++k) x2 += sP[k][t];
            const float inv1 = 1.0f / (1.0f + x2);
            const float xk2  = 4.0f * x2 * inv1 * inv1;
            const float g    = rsqrtf(fmaxf(1.0f - xk2, 1e-7f));
            float G = g;
            G += __shfl_xor(G, 1, 64);
            G += __shfl_xor(G, 2, 64);
            sA1[t] = 2.0f * g * inv1 / G;
        }
        BARRIER_LGKM();                                   // B2

        const float c0 = sA1[4 * j + 0];
        const float c1 = sA1[4 * j + 1];
        const float c2 = sA1[4 * j + 2];
        const float c3 = sA1[4 * j + 3];
        float mk[16];
        float q = 0.f;
        #pragma unroll
        for (int it = 0; it < 16; ++it) {
            const f4 vv = v[it];
            const float m = vv.x * c0 + vv.y * c1 + vv.z * c2 + vv.w * c3;
            mk[it] = m;
            q += m * m;
            if (i < TPB - 1)
                v[it] = __builtin_nontemporal_load((const f4*)(nsrc + (size_t)(it * 16 + rbase) * L_));
        }
        q += __shfl_xor(q, 32, 64);
        if (lane < 32) sQ[w][j] = q;
        BARRIER_LGKM();                                   // B3

        if (t < OT) {
            float m2 = 0.f;
            #pragma unroll
            for (int k = 0; k < 8; ++k) m2 += sQ[k][t];
            sInvm[t] = 1.0f / (1.0f + sqrtf(fmaxf(1.0f - m2, 1e-7f)));
        }
        BARRIER_LGKM();                                   // B4

        const float s = sInvm[j];
        #pragma unroll
        for (int it = 0; it < 16; ++it)
            __builtin_nontemporal_store(mk[it] * s,
                op + (size_t)(it * 16 + rbase) * OL_ + (size_t)i * OT);
    }
}

extern "C" void kernel_launch(void* const* d_in, const int* in_sizes, int n_in,
                              void* d_out, int out_size, void* d_ws, size_t ws_size,
                              hipStream_t stream) {
    const float* x = (const float*)d_in[0];
    float* out = (float*)d_out;
    // PROBE: 3 identical launches. K = (dur_us - 361)/2 vs single-launch R1.
    havgpool_hyp_kernel<<<dim3(NBLK), NTHR, 0, stream>>>(x, out);
    havgpool_hyp_kernel<<<dim3(NBLK), NTHR, 0, stream>>>(x, out);
    havgpool_hyp_kernel<<<dim3(NBLK), NTHR, 0, stream>>>(x, out);
}

// Round 3
// 350.612 us; speedup vs baseline: 1.3577x; 1.3577x over previous
//
#include <hip/hip_runtime.h>
#include <stdint.h>

// Reference: B=16, C=256, L=16384, K=S=4 -> OL=4096. fp32 in, fp32 out.
// FINAL (reverted from 3x measurement probe): single launch of the R0 kernel.
// Probe result (R2): per-launch kernel time K = (476.0-361.1)/2 = 57.5 us
// vs 53.3 us HBM roofline (335.5 MB @ 6.3 TB/s achievable) => ~93% of
// memory-bandwidth ceiling. Remaining dur_us (~300 us) is fixed harness
// poison/restore traffic (the 1 GiB fillBuffer alone is 161 us).
// Decomposition: block = (b, 128 consecutive l / 32 outputs). Thread t owns
// output j = t&31 (l-quad 4j..4j+3) for 16 channels -> window math fully in
// registers; only two tiny scalar reductions cross threads.
#define B_      16
#define C_      256
#define L_      16384
#define OL_     4096
#define OT      32     // outputs per block
#define TL      128    // input l per block (OT*4)
#define NTHR    512
#define OTILES  (OL_ / OT)   // 128

typedef float f4 __attribute__((ext_vector_type(4)));

__global__ __launch_bounds__(NTHR, 4)
void havgpool_hyp_kernel(const float* __restrict__ x, float* __restrict__ out) {
    __shared__ float sP[8][TL];    // per-wave sum_c(x^2) partials (4 KiB)
    __shared__ float sA1[TL];      // per-l combine coefficient
    __shared__ float sQ[8][OT];    // per-wave mK2 partials (1 KiB)
    __shared__ float sInvm[OT];    // per-o final scale

    const int t     = threadIdx.x;
    const int bid   = blockIdx.x;          // 0..2047, otile fastest
    const int otile = bid & (OTILES - 1);  // 0..127
    const int b     = bid >> 7;            // 0..15
    const int j     = t & 31;              // output / l-quad index
    const int rbase = t >> 5;              // channel-group 0..15
    const int lane  = t & 63;
    const int w     = t >> 6;              // wave 0..7

    // ---- Load 16 channels x 4 l into registers; squares accumulated in flight.
    // Per wave-load instruction: 2 rows x 512 B contiguous segments.
    const float* src = x + ((size_t)b * C_ * L_ + (size_t)otile * TL + 4 * j);
    f4 v[16];
    float a0 = 0.f, a1 = 0.f, a2 = 0.f, a3 = 0.f;
    #pragma unroll
    for (int it = 0; it < 16; ++it) {
        v[it] = __builtin_nontemporal_load((const f4*)(src + (size_t)(it * 16 + rbase) * L_));
        a0 += v[it].x * v[it].x;
        a1 += v[it].y * v[it].y;
        a2 += v[it].z * v[it].z;
        a3 += v[it].w * v[it].w;
    }
    // combine the two channel-groups in this wave (lanes j and j+32)
    a0 += __shfl_xor(a0, 32, 64);
    a1 += __shfl_xor(a1, 32, 64);
    a2 += __shfl_xor(a2, 32, 64);
    a3 += __shfl_xor(a3, 32, 64);
    if (lane < 32) {
        sP[w][4 * j + 0] = a0;
        sP[w][4 * j + 1] = a1;
        sP[w][4 * j + 2] = a2;
        sP[w][4 * j + 3] = a3;
    }
    __syncthreads();

    // ---- per-l scalars (waves 0-1): x2 -> gamma -> a1[l] = 2*gamma*inv1/G
    if (t < TL) {
        float x2 = 0.f;
        #pragma unroll
        for (int k = 0; k < 8; ++k) x2 += sP[k][t];          // stride-1: conflict-free
        const float inv1 = 1.0f / (1.0f + x2);
        const float xk2  = 4.0f * x2 * inv1 * inv1;          // sum_c xK^2
        const float g    = rsqrtf(fmaxf(1.0f - xk2, 1e-7f)); // gamma
        float G = g;                                         // sum over 4-window
        G += __shfl_xor(G, 1, 64);
        G += __shfl_xor(G, 2, 64);
        sA1[t] = 2.0f * g * inv1 / G;
    }
    __syncthreads();

    // ---- mK per (channel, output j) fully in registers
    const float c0 = sA1[4 * j + 0];
    const float c1 = sA1[4 * j + 1];
    const float c2 = sA1[4 * j + 2];
    const float c3 = sA1[4 * j + 3];
    float mk[16];
    float q = 0.f;                     // partial sum_c mK^2 for output j
    #pragma unroll
    for (int it = 0; it < 16; ++it) {
        mk[it] = v[it].x * c0 + v[it].y * c1 + v[it].z * c2 + v[it].w * c3;
        q += mk[it] * mk[it];
    }
    q += __shfl_xor(q, 32, 64);
    if (lane < 32) sQ[w][j] = q;
    __syncthreads();
    if (t < OT) {
        float m2 = 0.f;
        #pragma unroll
        for (int k = 0; k < 8; ++k) m2 += sQ[k][t];
        sInvm[t] = 1.0f / (1.0f + sqrtf(fmaxf(1.0f - m2, 1e-7f)));
    }
    __syncthreads();

    // ---- scale + store: per wave-store instruction, 2 rows x 128 B full lines
    const float s = sInvm[j];
    float* op = out + (size_t)(b * C_) * OL_ + (size_t)otile * OT + j;
    #pragma unroll
    for (int it = 0; it < 16; ++it) {
        __builtin_nontemporal_store(mk[it] * s, op + (size_t)(it * 16 + rbase) * OL_);
    }
}

extern "C" void kernel_launch(void* const* d_in, const int* in_sizes, int n_in,
                              void* d_out, int out_size, void* d_ws, size_t ws_size,
                              hipStream_t stream) {
    const float* x = (const float*)d_in[0];
    float* out = (float*)d_out;
    havgpool_hyp_kernel<<<dim3(OTILES * B_), NTHR, 0, stream>>>(x, out);
}